// Round 3
// baseline (204.983 us; speedup 1.0000x reference)
//
#include <hip/hip_runtime.h>

// LocallyConnected1d: out[b,o,i] = sum_{c,k} x[b,c,i+k] * w[o,c,i,k] + 64*bias[o,i]
// B=128, C_IN=64, C_OUT=64, L=1024, K=9, L_OUT=1016
//
// R3: single-pass GEMM reading raw w (f32, once, coalesced 288-B runs) + xt (bf16
// x-transpose from k1). Block = 8i x 16o x 128b, wave-per-i, c-chunks of 8,
// k padded 9->12. T14 prefetch across MFMA phase. Epilogue LDS-transpose ->
// 32-B i-run stores (kills R2-k3's 4.2x write amplification).

#define NB   128
#define CIN  64
#define COUT 64
#define LIN  1024
#define KW   9
#define LOUT 1016
#define KPAD 12

typedef __attribute__((ext_vector_type(4))) float f32x4;
typedef __attribute__((ext_vector_type(2))) float f32x2;
typedef __attribute__((ext_vector_type(8))) short bf16x8;

static __device__ __forceinline__ unsigned short f2bf(float f) {
    unsigned int u = __float_as_uint(f);
    u += 0x7fffu + ((u >> 16) & 1u);   // round-to-nearest-even
    return (unsigned short)(u >> 16);
}

// ---------------- K1: x[b][c][l] f32 -> xt[l][b*64+c] bf16 (16.8 MB) ----------------
__global__ __launch_bounds__(512) void k1_xt(const float* __restrict__ x,
                                             unsigned short* __restrict__ xt)
{
    __shared__ unsigned int T3[64][36];
    const int t  = threadIdx.x;
    const int b0 = ((int)blockIdx.x >> 4) * 4;
    const int l0 = ((int)blockIdx.x & 15) * 64;
    const int cp = t >> 4;
    const int lq = t & 15;

    for (int bb = 0; bb < 4; ++bb) {
        const int b = b0 + bb;
        const f32x4* x4 = (const f32x4*)x;
        f32x4 fa = x4[(size_t)(b * 64 + 2 * cp) * 256 + (l0 >> 2) + lq];
        f32x4 fb = x4[(size_t)(b * 64 + 2 * cp + 1) * 256 + (l0 >> 2) + lq];
        #pragma unroll
        for (int m = 0; m < 4; ++m) {
            unsigned int pk = (unsigned int)f2bf(fa[m]) | ((unsigned int)f2bf(fb[m]) << 16);
            T3[lq * 4 + m][cp] = pk;
        }
        __syncthreads();
        {
            const int lp = t >> 3;
            const int fq = t & 7;
            uint4 v = *(const uint4*)&T3[lp][fq * 4];
            *(uint4*)&xt[(size_t)(l0 + lp) * 8192 + b * 64 + fq * 8] = v;
        }
        __syncthreads();
    }
}

// ---------------- K2: single-pass GEMM ----------------
// grid 508 = 127 i-tiles(8) x 4 o-tiles(16). 512 thr = 8 waves; wave w = local i.
// LDS: Xw[19 rows][128 b][8 c] bf16 (38912 B) | Ws[8 i][12 k][16 o][8 c] bf16 (24576 B)
//      epilogue reuses smem as Cb[8 i][128 b][16 o] f32 (65536 B)
__global__ __launch_bounds__(512, 4) void k2_gemm(const unsigned short* __restrict__ xt,
                                                  const float* __restrict__ w,
                                                  const float* __restrict__ bias,
                                                  float* __restrict__ out)
{
    __shared__ char smem[65536];
    unsigned short* Xw = (unsigned short*)smem;            // 19*128*8 u16
    unsigned short* Ws = (unsigned short*)(smem + 39168);  // 8*12*16*8 u16
    float* Cb = (float*)smem;                              // 8*128*16 f32

    // bijective XCD-chunked swizzle over 508 blocks (q=63, r=4): consecutive
    // vid within an XCD chunk = consecutive i-tiles -> store half-lines merge in L2.
    const int orig = (int)blockIdx.x;
    const int xcd = orig & 7, sidx = orig >> 3;
    const int vid = (xcd < 4) ? xcd * 64 + sidx : 256 + (xcd - 4) * 63 + sidx;
    const int it = vid % 127;
    const int ob = vid / 127;
    const int i0 = it * 8;
    const int o0 = ob * 16;

    const int t    = threadIdx.x;
    const int iloc = t >> 6;          // wave id = local i
    const int lane = t & 63;
    const int l16  = lane & 15;
    const int l4   = lane >> 4;

    // zero the k=9..11 pad region of Ws (never rewritten)
    for (int z = t; z < 1536; z += 512) {
        int zi = z / 192, zr = z - zi * 192;
        ((unsigned int*)Ws)[(zi * KPAD + 9) * 64 + zr] = 0;
    }

    f32x4 acc[8];
    #pragma unroll
    for (int m = 0; m < 8; ++m) acc[m] = (f32x4){0.f, 0.f, 0.f, 0.f};

    // staging roles
    const int run  = t >> 2;          // 0..127 : (o, c_loc)
    const int part = t & 3;           // quarter of the 72-f32 run (18 f32 = 2 i x 9 k)
    const int so   = run >> 3;        // 0..15
    const int scl  = run & 7;         // 0..7

    // prologue loads (cc = 0)
    uint4 xv[5];
    f32x2 wv[9];
    #pragma unroll
    for (int j = 0; j < 5; ++j) {
        int e = t + j * 512;
        if (e < 2432) {
            int row = e >> 7, b = e & 127;
            int l = i0 + row; if (l > 1023) l = 1023;
            xv[j] = *(const uint4*)&xt[(size_t)l * 8192 + b * 64 + 0 * 8];
        }
    }
    {
        const float* wp = w + ((size_t)(o0 + so) * 64 + 0 * 8 + scl) * (LOUT * 9)
                            + (size_t)i0 * 9 + part * 18;
        #pragma unroll
        for (int q = 0; q < 9; ++q) wv[q] = *(const f32x2*)(wp + 2 * q);
    }

    for (int cc = 0; cc < 8; ++cc) {
        // ---- stage: regs -> LDS ----
        #pragma unroll
        for (int j = 0; j < 5; ++j) {
            int e = t + j * 512;
            if (e < 2432) *(uint4*)&Xw[e * 8] = xv[j];
        }
        #pragma unroll
        for (int s = 0; s < 18; ++s) {
            float v = ((const float*)wv)[s];
            int ii = part * 2 + (s >= 9 ? 1 : 0);
            int kk = (s >= 9) ? s - 9 : s;
            Ws[((ii * KPAD + kk) * 16 + so) * 8 + scl] = f2bf(v);
        }
        __syncthreads();

        // ---- prefetch next c-chunk (hidden under MFMA phase) ----
        if (cc < 7) {
            int cn = cc + 1;
            #pragma unroll
            for (int j = 0; j < 5; ++j) {
                int e = t + j * 512;
                if (e < 2432) {
                    int row = e >> 7, b = e & 127;
                    int l = i0 + row; if (l > 1023) l = 1023;
                    xv[j] = *(const uint4*)&xt[(size_t)l * 8192 + b * 64 + cn * 8];
                }
            }
            const float* wp = w + ((size_t)(o0 + so) * 64 + cn * 8 + scl) * (LOUT * 9)
                                + (size_t)i0 * 9 + part * 18;
            #pragma unroll
            for (int q = 0; q < 9; ++q) wv[q] = *(const f32x2*)(wp + 2 * q);
        }

        // ---- MFMA phase: 3 K-chunks of 32 (4k x 8c), wave = i, all 8 m-slices ----
        #pragma unroll
        for (int kp = 0; kp < 3; ++kp) {
            const int k0 = kp * 4;
            bf16x8 bf = *(const bf16x8*)&Ws[((iloc * KPAD + k0 + l4) * 16 + l16) * 8];
            #pragma unroll
            for (int m = 0; m < 8; ++m) {
                bf16x8 af = *(const bf16x8*)&Xw[((iloc + k0 + l4) * 128 + m * 16 + l16) * 8];
                acc[m] = __builtin_amdgcn_mfma_f32_16x16x32_bf16(af, bf, acc[m], 0, 0, 0);
            }
        }
        __syncthreads();
    }

    // ---- epilogue: acc -> Cb[i][b][o] -> 32-B i-run stores ----
    #pragma unroll
    for (int m = 0; m < 8; ++m) {
        int b = m * 16 + l4 * 4;
        #pragma unroll
        for (int jj = 0; jj < 4; ++jj)
            Cb[((size_t)iloc * 128 + b + jj) * 16 + l16] = acc[m][jj];
    }
    __syncthreads();

    {
        const int b  = t >> 2;
        const int og = (t & 3) * 4;
        #pragma unroll
        for (int s = 0; s < 4; ++s) {
            const int o = og + s;
            f32x4 bv0 = *(const f32x4*)&bias[(size_t)(o0 + o) * LOUT + i0];
            f32x4 bv1 = *(const f32x4*)&bias[(size_t)(o0 + o) * LOUT + i0 + 4];
            f32x4 v0, v1;
            #pragma unroll
            for (int ii = 0; ii < 4; ++ii) v0[ii] = Cb[(ii * 128 + b) * 16 + o] + 64.0f * bv0[ii];
            #pragma unroll
            for (int ii = 0; ii < 4; ++ii) v1[ii] = Cb[((ii + 4) * 128 + b) * 16 + o] + 64.0f * bv1[ii];
            float* op = &out[((size_t)b * 64 + (o0 + o)) * LOUT + i0];
            *(f32x4*)op = v0;
            *(f32x4*)(op + 4) = v1;
        }
    }
}

// ---------------- fallback (tiny ws): R1 direct kernel ----------------
__global__ __launch_bounds__(512, 4) void lc1d_legacy(
    const float* __restrict__ x, const float* __restrict__ w,
    const float* __restrict__ bias, float* __restrict__ out)
{
    const int i    = ((int)(blockIdx.x & 7)) * 127 + ((int)blockIdx.x >> 3);
    const int tid  = threadIdx.x;
    const int lane = tid & 63;
    const int wid  = tid >> 6;
    const int wm   = wid >> 1;
    const int wn   = wid & 1;
    const int l16  = lane & 15;
    const int l4   = lane >> 4;

    __shared__ unsigned short Alds[128][40];
    __shared__ unsigned short Blds[64][40];

    f32x4 acc[2][2];
    #pragma unroll
    for (int a = 0; a < 2; ++a)
        #pragma unroll
        for (int b = 0; b < 2; ++b)
            acc[a][b] = (f32x4){0.f, 0.f, 0.f, 0.f};

    for (int tch = 0; tch < 18; ++tch) {
        const int q0 = tch * 32;
        #pragma unroll
        for (int j = 0; j < 4; ++j) {
            int e = tid + j * 512;
            int o = e >> 5, qq = e & 31;
            int q = q0 + qq;
            int c = q / 9, k = q - 9 * c;
            Blds[o][qq] = f2bf(w[((size_t)(o * CIN + c) * LOUT + i) * KW + k]);
        }
        #pragma unroll
        for (int j = 0; j < 8; ++j) {
            int e = tid + j * 512;
            int b = e >> 5, qq = e & 31;
            int q = q0 + qq;
            int c = q / 9, k = q - 9 * c;
            Alds[b][qq] = f2bf(x[(size_t)(b * CIN + c) * LIN + i + k]);
        }
        __syncthreads();
        bf16x8 af[2], bfr[2];
        #pragma unroll
        for (int mf = 0; mf < 2; ++mf)
            af[mf] = *reinterpret_cast<const bf16x8*>(&Alds[wm * 32 + mf * 16 + l16][l4 * 8]);
        #pragma unroll
        for (int nf = 0; nf < 2; ++nf)
            bfr[nf] = *reinterpret_cast<const bf16x8*>(&Blds[wn * 32 + nf * 16 + l16][l4 * 8]);
        #pragma unroll
        for (int mf = 0; mf < 2; ++mf)
            #pragma unroll
            for (int nf = 0; nf < 2; ++nf)
                acc[mf][nf] = __builtin_amdgcn_mfma_f32_16x16x32_bf16(af[mf], bfr[nf], acc[mf][nf], 0, 0, 0);
        __syncthreads();
    }
    #pragma unroll
    for (int nf = 0; nf < 2; ++nf) {
        int o = wn * 32 + nf * 16 + l16;
        float bv = 64.0f * bias[o * LOUT + i];
        #pragma unroll
        for (int mf = 0; mf < 2; ++mf)
            #pragma unroll
            for (int j = 0; j < 4; ++j) {
                int b = wm * 32 + mf * 16 + l4 * 4 + j;
                out[((size_t)b * 64 + o) * LOUT + i] = acc[mf][nf][j] + bv;
            }
    }
}

extern "C" void kernel_launch(void* const* d_in, const int* in_sizes, int n_in,
                              void* d_out, int out_size, void* d_ws, size_t ws_size,
                              hipStream_t stream) {
    const float* x    = (const float*)d_in[0];
    const float* w    = (const float*)d_in[1];
    const float* bias = (const float*)d_in[2];
    float* out        = (float*)d_out;

    const size_t XTB = (size_t)1024 * 128 * 64 * 2;   // 16,777,216

    if (ws_size < XTB) {
        lc1d_legacy<<<dim3(LOUT), dim3(512), 0, stream>>>(x, w, bias, out);
        return;
    }
    unsigned short* xt = (unsigned short*)d_ws;

    k1_xt  <<<dim3(512), dim3(512), 0, stream>>>(x, xt);
    k2_gemm<<<dim3(508), dim3(512), 0, stream>>>(xt, w, bias, out);
}

// Round 4
// 137.675 us; speedup vs baseline: 1.4889x; 1.4889x over previous
//
#include <hip/hip_runtime.h>

// LocallyConnected1d: out[b,o,i] = sum_{c,k} x[b,c,i+k] * w[o,c,i,k] + 64*bias[o,i]
// B=128, C_IN=64, C_OUT=64, L=1024, K=9, L_OUT=1016
//
// R4 pipeline:
//   k1: x[b][c][l] f32 -> xt[l][b*64+c] bf16          (16.8 MB)   [measured ~8us]
//   k2: w[o][c][i][k] f32 -> w2[i][o][k*64+c] bf16    (74.9 MB)   [measured ~45us, ~5TB/s]
//   k3d: per-i GEMM (M=128,N=64,K=576) reading xt+w2, T14 reg-prefetch,
//        output -> cws[i][b*64+o] f32 (block-contiguous FULL-LINE writes; kills
//        R2-k3's 139MB write-amp + R3's ~165MB RFO fetch)
//   k4: transpose cws[i][bo] -> out[b][o][i] (full lines both sides)

#define NB   128
#define CIN  64
#define COUT 64
#define LIN  1024
#define KW   9
#define LOUT 1016

typedef __attribute__((ext_vector_type(4))) float f32x4;
typedef __attribute__((ext_vector_type(8))) short bf16x8;

static __device__ __forceinline__ unsigned short f2bf(float f) {
    unsigned int u = __float_as_uint(f);
    u += 0x7fffu + ((u >> 16) & 1u);   // round-to-nearest-even
    return (unsigned short)(u >> 16);
}

// ---------------- K1: x[b][c][l] f32 -> xt[l][b*64+c] bf16 ----------------
__global__ __launch_bounds__(512) void k1_xt(const float* __restrict__ x,
                                             unsigned short* __restrict__ xt)
{
    __shared__ unsigned int T3[64][36];
    const int t  = threadIdx.x;
    const int b0 = ((int)blockIdx.x >> 4) * 4;
    const int l0 = ((int)blockIdx.x & 15) * 64;
    const int cp = t >> 4;
    const int lq = t & 15;

    for (int bb = 0; bb < 4; ++bb) {
        const int b = b0 + bb;
        const f32x4* x4 = (const f32x4*)x;
        f32x4 fa = x4[(size_t)(b * 64 + 2 * cp) * 256 + (l0 >> 2) + lq];
        f32x4 fb = x4[(size_t)(b * 64 + 2 * cp + 1) * 256 + (l0 >> 2) + lq];
        #pragma unroll
        for (int m = 0; m < 4; ++m) {
            unsigned int pk = (unsigned int)f2bf(fa[m]) | ((unsigned int)f2bf(fb[m]) << 16);
            T3[lq * 4 + m][cp] = pk;
        }
        __syncthreads();
        {
            const int lp = t >> 3;
            const int fq = t & 7;
            uint4 v = *(const uint4*)&T3[lp][fq * 4];
            *(uint4*)&xt[(size_t)(l0 + lp) * 8192 + b * 64 + fq * 8] = v;
        }
        __syncthreads();
    }
}

// ---------------- K2: w[o][c][i][k] f32 -> w2[((i*64+o)*576) + k*64+c] bf16 ----------------
__global__ __launch_bounds__(512) void k2_w2(const float* __restrict__ w,
                                             unsigned short* __restrict__ w2)
{
    __shared__ unsigned short T2[32][584];
    const int t  = threadIdx.x;
    const int o  = (int)blockIdx.x & 63;
    const int it = (int)blockIdx.x >> 6;
    const int i0 = it * 32;
    const int n_i = (LOUT - i0) < 32 ? (LOUT - i0) : 32;   // 32 or 24
    const int f4cnt = (n_i * 9) >> 2;                      // 72 or 54 (exact)
    const int c = t >> 3;
    const int g = t & 7;
    const f32x4* w4 = (const f32x4*)w;
    const size_t cbase = (size_t)(o * 64 + c) * 2286 + (size_t)it * 72;

    for (int f4i = g; f4i < f4cnt; f4i += 8) {
        f32x4 v = w4[cbase + f4i];
        #pragma unroll
        for (int m = 0; m < 4; ++m) {
            int e  = f4i * 4 + m;
            int ii = (e * 7282) >> 16;        // e/9
            int k  = e - ii * 9;
            T2[ii][k * 64 + c] = f2bf(v[m]);
        }
    }
    __syncthreads();
    const int flat = n_i * 72;
    for (int idx = t; idx < flat; idx += 512) {
        int ii = (int)(((unsigned)idx * 58255u) >> 22);   // idx/72
        int qo = idx - ii * 72;
        uint4 v = *(const uint4*)&T2[ii][qo * 8];
        *(uint4*)&w2[((size_t)(i0 + ii) * 64 + o) * 576 + qo * 8] = v;
    }
}

// ---------------- K3d: per-i GEMM -> cws[i][b*64+o] ----------------
__global__ __launch_bounds__(512, 4) void k3d(const unsigned short* __restrict__ xt,
                                              const unsigned short* __restrict__ w2,
                                              const float* __restrict__ bias,
                                              float* __restrict__ cws)
{
    __shared__ union {
        struct { unsigned short A[128][72]; unsigned short B[64][72]; } s;  // 27648 B
        float Cb[128][68];                                                  // 34816 B
    } u;
    __shared__ float Bv[64];

    // bijective XCD swizzle (1016 = 8*127): XCD k owns contiguous i-range
    const int i    = ((int)(blockIdx.x & 7)) * 127 + ((int)blockIdx.x >> 3);
    const int t    = threadIdx.x;
    const int lane = t & 63;
    const int wid  = t >> 6;
    const int wm   = wid >> 1, wn = wid & 1;
    const int l16  = lane & 15, l4 = lane >> 4;

    if (t < 64) Bv[t] = 64.0f * bias[(size_t)t * LOUT + i];

    f32x4 acc[2][2];
    #pragma unroll
    for (int a = 0; a < 2; ++a)
        #pragma unroll
        for (int b = 0; b < 2; ++b)
            acc[a][b] = (f32x4){0.f, 0.f, 0.f, 0.f};

    const int ab = t >> 2, aq = (t & 3) * 16;   // A staging role
    const int bo = t >> 3, bq = (t & 7) * 8;    // B staging role

    // prologue: load kk=0 to regs
    uint4 va0 = *(const uint4*)&xt[(size_t)i * 8192 + ab * 64 + aq];
    uint4 va1 = *(const uint4*)&xt[(size_t)i * 8192 + ab * 64 + aq + 8];
    uint4 vb  = *(const uint4*)&w2[((size_t)i * 64 + bo) * 576 + bq];

    for (int kk = 0; kk < 9; ++kk) {
        // stage regs -> LDS (frees regs)
        *(uint4*)&u.s.A[ab][aq]     = va0;
        *(uint4*)&u.s.A[ab][aq + 8] = va1;
        *(uint4*)&u.s.B[bo][bq]     = vb;
        // T14: issue next iter's loads NOW; in flight across barrier+MFMA+barrier
        if (kk < 8) {
            va0 = *(const uint4*)&xt[(size_t)(i + kk + 1) * 8192 + ab * 64 + aq];
            va1 = *(const uint4*)&xt[(size_t)(i + kk + 1) * 8192 + ab * 64 + aq + 8];
            vb  = *(const uint4*)&w2[((size_t)i * 64 + bo) * 576 + (kk + 1) * 64 + bq];
        }
        __syncthreads();
        #pragma unroll
        for (int ks = 0; ks < 2; ++ks) {
            bf16x8 af[2], bfr[2];
            #pragma unroll
            for (int mf = 0; mf < 2; ++mf)
                af[mf] = *(const bf16x8*)&u.s.A[wm * 32 + mf * 16 + l16][ks * 32 + l4 * 8];
            #pragma unroll
            for (int nf = 0; nf < 2; ++nf)
                bfr[nf] = *(const bf16x8*)&u.s.B[wn * 32 + nf * 16 + l16][ks * 32 + l4 * 8];
            #pragma unroll
            for (int mf = 0; mf < 2; ++mf)
                #pragma unroll
                for (int nf = 0; nf < 2; ++nf)
                    acc[mf][nf] = __builtin_amdgcn_mfma_f32_16x16x32_bf16(
                        af[mf], bfr[nf], acc[mf][nf], 0, 0, 0);
        }
        __syncthreads();
    }

    // epilogue: acc -> Cb (LDS transpose), then full-line stores to cws[i][b*64+o]
    // C/D layout (m89): col = lane&15 (=o), row = (lane>>4)*4 + reg (=b)
    #pragma unroll
    for (int nf = 0; nf < 2; ++nf) {
        int o = wn * 32 + nf * 16 + l16;
        #pragma unroll
        for (int mf = 0; mf < 2; ++mf)
            #pragma unroll
            for (int j = 0; j < 4; ++j)
                u.Cb[wm * 32 + mf * 16 + l4 * 4 + j][o] = acc[mf][nf][j];
    }
    __syncthreads();
    float* crow = &cws[(size_t)i * 8192];
    #pragma unroll
    for (int f = 0; f < 4; ++f) {
        int idx = (f * 512 + t) * 4;
        int b = idx >> 6, o = idx & 63;
        f32x4 v = *(const f32x4*)&u.Cb[b][o];
        v[0] += Bv[o]; v[1] += Bv[o + 1]; v[2] += Bv[o + 2]; v[3] += Bv[o + 3];
        *(f32x4*)&crow[idx] = v;
    }
}

// ---------------- K4: cws[i][bo] -> out[bo][i] transpose ----------------
__global__ __launch_bounds__(256) void k4_tr(const float* __restrict__ cws,
                                             float* __restrict__ out)
{
    __shared__ float T[128][68];
    const int bo0 = ((int)blockIdx.x & 127) * 64;
    const int ic  = (int)blockIdx.x >> 7;            // 0..7
    const int ni  = (ic == 7) ? 120 : 128;           // 1016 = 7*128 + 120
    const int t   = threadIdx.x;

    #pragma unroll
    for (int j = 0; j < 32; ++j) {
        int e = t + j * 256;
        int iloc = e >> 4, boq = (e & 15) * 4;
        if (iloc < ni)
            *(f32x4*)&T[iloc][boq] =
                *(const f32x4*)&cws[(size_t)(ic * 128 + iloc) * 8192 + bo0 + boq];
    }
    __syncthreads();

    const int boloc = t >> 2, ig = t & 3;
    #pragma unroll
    for (int jj = 0; jj < 8; ++jj) {
        int ii = ig * 32 + jj * 4;
        if (ii + 4 <= ni) {
            f32x4 v = {T[ii][boloc], T[ii + 1][boloc], T[ii + 2][boloc], T[ii + 3][boloc]};
            *(f32x4*)&out[(size_t)(bo0 + boloc) * LOUT + ic * 128 + ii] = v;
        }
    }
}

// ---------------- fallback (tiny ws): direct scattered-read GEMM ----------------
__global__ __launch_bounds__(512, 4) void lc1d_legacy(
    const float* __restrict__ x, const float* __restrict__ w,
    const float* __restrict__ bias, float* __restrict__ out)
{
    const int i    = ((int)(blockIdx.x & 7)) * 127 + ((int)blockIdx.x >> 3);
    const int tid  = threadIdx.x;
    const int lane = tid & 63;
    const int wid  = tid >> 6;
    const int wm   = wid >> 1;
    const int wn   = wid & 1;
    const int l16  = lane & 15;
    const int l4   = lane >> 4;

    __shared__ unsigned short Alds[128][40];
    __shared__ unsigned short Blds[64][40];

    f32x4 acc[2][2];
    #pragma unroll
    for (int a = 0; a < 2; ++a)
        #pragma unroll
        for (int b = 0; b < 2; ++b)
            acc[a][b] = (f32x4){0.f, 0.f, 0.f, 0.f};

    for (int tch = 0; tch < 18; ++tch) {
        const int q0 = tch * 32;
        #pragma unroll
        for (int j = 0; j < 4; ++j) {
            int e = tid + j * 512;
            int o = e >> 5, qq = e & 31;
            int q = q0 + qq;
            int c = q / 9, k = q - 9 * c;
            Blds[o][qq] = f2bf(w[((size_t)(o * CIN + c) * LOUT + i) * KW + k]);
        }
        #pragma unroll
        for (int j = 0; j < 8; ++j) {
            int e = tid + j * 512;
            int b = e >> 5, qq = e & 31;
            int q = q0 + qq;
            int c = q / 9, k = q - 9 * c;
            Alds[b][qq] = f2bf(x[(size_t)(b * CIN + c) * LIN + i + k]);
        }
        __syncthreads();
        bf16x8 af[2], bfr[2];
        #pragma unroll
        for (int mf = 0; mf < 2; ++mf)
            af[mf] = *reinterpret_cast<const bf16x8*>(&Alds[wm * 32 + mf * 16 + l16][l4 * 8]);
        #pragma unroll
        for (int nf = 0; nf < 2; ++nf)
            bfr[nf] = *reinterpret_cast<const bf16x8*>(&Blds[wn * 32 + nf * 16 + l16][l4 * 8]);
        #pragma unroll
        for (int mf = 0; mf < 2; ++mf)
            #pragma unroll
            for (int nf = 0; nf < 2; ++nf)
                acc[mf][nf] = __builtin_amdgcn_mfma_f32_16x16x32_bf16(af[mf], bfr[nf], acc[mf][nf], 0, 0, 0);
        __syncthreads();
    }
    #pragma unroll
    for (int nf = 0; nf < 2; ++nf) {
        int o = wn * 32 + nf * 16 + l16;
        float bv = 64.0f * bias[o * LOUT + i];
        #pragma unroll
        for (int mf = 0; mf < 2; ++mf)
            #pragma unroll
            for (int j = 0; j < 4; ++j) {
                int b = wm * 32 + mf * 16 + l4 * 4 + j;
                out[((size_t)b * 64 + o) * LOUT + i] = acc[mf][nf][j] + bv;
            }
    }
}

extern "C" void kernel_launch(void* const* d_in, const int* in_sizes, int n_in,
                              void* d_out, int out_size, void* d_ws, size_t ws_size,
                              hipStream_t stream) {
    const float* x    = (const float*)d_in[0];
    const float* w    = (const float*)d_in[1];
    const float* bias = (const float*)d_in[2];
    float* out        = (float*)d_out;

    const size_t W2B = (size_t)LOUT * 64 * 576 * 2;      // 74,907,648
    const size_t XTB = (size_t)1024 * 128 * 64 * 2;      // 16,777,216
    const size_t CWB = (size_t)LOUT * 8192 * 4;          // 33,292,288

    if (ws_size < W2B + XTB + CWB) {
        lc1d_legacy<<<dim3(LOUT), dim3(512), 0, stream>>>(x, w, bias, out);
        return;
    }
    unsigned short* w2 = (unsigned short*)d_ws;
    unsigned short* xt = (unsigned short*)((char*)d_ws + W2B);
    float*          cw = (float*)((char*)d_ws + W2B + XTB);

    k1_xt <<<dim3(512),  dim3(512), 0, stream>>>(x, xt);
    k2_w2 <<<dim3(2048), dim3(512), 0, stream>>>(w, w2);
    k3d   <<<dim3(LOUT), dim3(512), 0, stream>>>(xt, w2, bias, cw);
    k4_tr <<<dim3(1024), dim3(256), 0, stream>>>(cw, out);
}

// Round 5
// 109.961 us; speedup vs baseline: 1.8641x; 1.2520x over previous
//
#include <hip/hip_runtime.h>

// LocallyConnected1d: out[b,o,i] = sum_{c,k} x[b,c,i+k] * w[o,c,i,k] + 64*bias[o,i]
// B=128, C_IN=64, C_OUT=64, L=1024, K=9, L_OUT=1016
//
// R5 pipeline:
//   k1: x[b][c][l] f32 -> xt[l][b*64+c] bf16          (~8us, measured)
//   k2: w[o][c][i][k] f32 -> w2[i][o][k*64+c] bf16    (~45us @ ~5TB/s, measured)
//   k3e: per-i GEMM; T3/T4 3-buffer global_load_lds pipeline, counted vmcnt(3),
//        raw s_barrier (1/iter), XOR-swizzled source+read (rule #21). -> cws full-line.
//   k4: cws[i][bo] -> out[bo][i] transpose (~12us)

#define NB   128
#define CIN  64
#define COUT 64
#define LIN  1024
#define KW   9
#define LOUT 1016

typedef __attribute__((ext_vector_type(4))) float f32x4;
typedef __attribute__((ext_vector_type(8))) short bf16x8;

typedef const __attribute__((address_space(1))) unsigned int* gptr_t;
typedef __attribute__((address_space(3))) unsigned int* lptr_t;

static __device__ __forceinline__ unsigned short f2bf(float f) {
    unsigned int u = __float_as_uint(f);
    u += 0x7fffu + ((u >> 16) & 1u);   // round-to-nearest-even
    return (unsigned short)(u >> 16);
}

// ---------------- K1: x[b][c][l] f32 -> xt[l][b*64+c] bf16 ----------------
__global__ __launch_bounds__(512) void k1_xt(const float* __restrict__ x,
                                             unsigned short* __restrict__ xt)
{
    __shared__ unsigned int T3[64][36];
    const int t  = threadIdx.x;
    const int b0 = ((int)blockIdx.x >> 4) * 4;
    const int l0 = ((int)blockIdx.x & 15) * 64;
    const int cp = t >> 4;
    const int lq = t & 15;

    for (int bb = 0; bb < 4; ++bb) {
        const int b = b0 + bb;
        const f32x4* x4 = (const f32x4*)x;
        f32x4 fa = x4[(size_t)(b * 64 + 2 * cp) * 256 + (l0 >> 2) + lq];
        f32x4 fb = x4[(size_t)(b * 64 + 2 * cp + 1) * 256 + (l0 >> 2) + lq];
        #pragma unroll
        for (int m = 0; m < 4; ++m) {
            unsigned int pk = (unsigned int)f2bf(fa[m]) | ((unsigned int)f2bf(fb[m]) << 16);
            T3[lq * 4 + m][cp] = pk;
        }
        __syncthreads();
        {
            const int lp = t >> 3;
            const int fq = t & 7;
            uint4 v = *(const uint4*)&T3[lp][fq * 4];
            *(uint4*)&xt[(size_t)(l0 + lp) * 8192 + b * 64 + fq * 8] = v;
        }
        __syncthreads();
    }
}

// ---------------- K2: w[o][c][i][k] f32 -> w2[((i*64+o)*576) + k*64+c] bf16 ----------------
__global__ __launch_bounds__(512) void k2_w2(const float* __restrict__ w,
                                             unsigned short* __restrict__ w2)
{
    __shared__ unsigned short T2[32][584];
    const int t  = threadIdx.x;
    const int o  = (int)blockIdx.x & 63;
    const int it = (int)blockIdx.x >> 6;
    const int i0 = it * 32;
    const int n_i = (LOUT - i0) < 32 ? (LOUT - i0) : 32;   // 32 or 24
    const int f4cnt = (n_i * 9) >> 2;                      // 72 or 54 (exact)
    const int c = t >> 3;
    const int g = t & 7;
    const f32x4* w4 = (const f32x4*)w;
    const size_t cbase = (size_t)(o * 64 + c) * 2286 + (size_t)it * 72;

    for (int f4i = g; f4i < f4cnt; f4i += 8) {
        f32x4 v = w4[cbase + f4i];
        #pragma unroll
        for (int m = 0; m < 4; ++m) {
            int e  = f4i * 4 + m;
            int ii = (e * 7282) >> 16;        // e/9
            int k  = e - ii * 9;
            T2[ii][k * 64 + c] = f2bf(v[m]);
        }
    }
    __syncthreads();
    const int flat = n_i * 72;
    for (int idx = t; idx < flat; idx += 512) {
        int ii = (int)(((unsigned)idx * 58255u) >> 22);   // idx/72
        int qo = idx - ii * 72;
        uint4 v = *(const uint4*)&T2[ii][qo * 8];
        *(uint4*)&w2[((size_t)(i0 + ii) * 64 + o) * 576 + qo * 8] = v;
    }
}

// ---------------- K3e: per-i GEMM, 3-buffer gload_lds pipeline -> cws[i][b*64+o] ----------------
// LDS: 3 x { A[128 b][64 q] 16KB | B[64 o][64 q] 8KB } = 72KB, linear (gload_lds),
//      logical granule lg stored at lg^(row&7)  (T2-style swizzle via source+read).
// Epilogue Cb[128][68] f32 overlays buffers 0-1 (34816 < 49152; buf2 untouched).
#define BUFSZ 24576
__global__ __launch_bounds__(512, 4) void k3e(const unsigned short* __restrict__ xt,
                                              const unsigned short* __restrict__ w2,
                                              const float* __restrict__ bias,
                                              float* __restrict__ cws)
{
    __shared__ __align__(16) char smem[3 * BUFSZ + 256];
    float* Bv = (float*)(smem + 3 * BUFSZ);
    float* Cb = (float*)smem;   // [128][68]

    const int i    = ((int)(blockIdx.x & 7)) * 127 + ((int)blockIdx.x >> 3);  // bijective XCD swizzle
    const int t    = threadIdx.x;
    const int lane = t & 63;
    const int wid  = t >> 6;
    const int wm   = wid >> 1, wn = wid & 1;
    const int l16  = lane & 15, l4 = lane >> 4;

    // staging source offsets (u16 units), source-side XOR swizzle
    int offA[2];
    #pragma unroll
    for (int j = 0; j < 2; ++j) {
        int e = t + j * 512, b = e >> 3, g = e & 7;
        offA[j] = b * 64 + ((g ^ (b & 7)) << 3);
    }
    const int ob = t >> 3, og = t & 7;
    const size_t offB = (size_t)((size_t)i * 64 + ob) * 576 + (size_t)((og ^ (ob & 7)) << 3);
    // wave-uniform LDS byte bases for gload_lds (HW adds lane*16)
    const int ldsA0 = (wid * 64) * 16;            // + j*512*16
    const int ldsB0 = 16384 + (wid * 64) * 16;

    f32x4 acc[2][2];
    #pragma unroll
    for (int a = 0; a < 2; ++a)
        #pragma unroll
        for (int b = 0; b < 2; ++b)
            acc[a][b] = (f32x4){0.f, 0.f, 0.f, 0.f};

    auto issue = [&](int kk) {
        char* base = smem + (kk % 3) * BUFSZ;
        const unsigned short* ga = xt + (size_t)(i + kk) * 8192;
        #pragma unroll
        for (int j = 0; j < 2; ++j)
            __builtin_amdgcn_global_load_lds((gptr_t)(const void*)(ga + offA[j]),
                                             (lptr_t)(void*)(base + ldsA0 + j * 8192),
                                             16, 0, 0);
        __builtin_amdgcn_global_load_lds((gptr_t)(const void*)(w2 + offB + (size_t)kk * 64),
                                         (lptr_t)(void*)(base + ldsB0),
                                         16, 0, 0);
    };

    issue(0);
    issue(1);

    for (int kk = 0; kk < 9; ++kk) {
        if (kk < 8) { asm volatile("s_waitcnt vmcnt(3)" ::: "memory"); }
        else        { asm volatile("s_waitcnt vmcnt(0)" ::: "memory"); }
        __builtin_amdgcn_sched_barrier(0);
        __builtin_amdgcn_s_barrier();      // buf[kk] landed for all waves; buf[kk-1] reads done
        if (kk + 2 <= 8) issue(kk + 2);    // into buf[(kk+2)%3] == buf[(kk-1)%3], now free

        const char* Ab = smem + (kk % 3) * BUFSZ;
        const char* Bb = Ab + 16384;
        #pragma unroll
        for (int ks = 0; ks < 2; ++ks) {
            bf16x8 af[2], bfr[2];
            #pragma unroll
            for (int mf = 0; mf < 2; ++mf) {
                int r = wm * 32 + mf * 16 + l16;
                af[mf] = *(const bf16x8*)(Ab + r * 128 + (((ks * 4 + l4) ^ (r & 7)) << 4));
            }
            #pragma unroll
            for (int nf = 0; nf < 2; ++nf) {
                int o = wn * 32 + nf * 16 + l16;
                bfr[nf] = *(const bf16x8*)(Bb + o * 128 + (((ks * 4 + l4) ^ (o & 7)) << 4));
            }
            #pragma unroll
            for (int mf = 0; mf < 2; ++mf)
                #pragma unroll
                for (int nf = 0; nf < 2; ++nf)
                    acc[mf][nf] = __builtin_amdgcn_mfma_f32_16x16x32_bf16(
                        af[mf], bfr[nf], acc[mf][nf], 0, 0, 0);
        }
        asm volatile("" ::: "memory");
    }

    // epilogue: bias, acc -> Cb (bufs 0-1 region; all reads of bufs 0-1 completed),
    // then full-line stores to cws[i][b*64+o]
    if (t < 64) Bv[t] = 64.0f * bias[(size_t)t * LOUT + i];
    // C/D layout (m89): col = lane&15 (=o), row = (lane>>4)*4 + reg (=b)
    #pragma unroll
    for (int nf = 0; nf < 2; ++nf) {
        int o = wn * 32 + nf * 16 + l16;
        #pragma unroll
        for (int mf = 0; mf < 2; ++mf)
            #pragma unroll
            for (int j = 0; j < 4; ++j)
                Cb[(size_t)(wm * 32 + mf * 16 + l4 * 4 + j) * 68 + o] = acc[mf][nf][j];
    }
    __syncthreads();
    float* crow = &cws[(size_t)i * 8192];
    #pragma unroll
    for (int f = 0; f < 4; ++f) {
        int idx = (f * 512 + t) * 4;
        int b = idx >> 6, o = idx & 63;
        f32x4 v = *(const f32x4*)&Cb[(size_t)b * 68 + o];
        v[0] += Bv[o]; v[1] += Bv[o + 1]; v[2] += Bv[o + 2]; v[3] += Bv[o + 3];
        *(f32x4*)&crow[idx] = v;
    }
}

// ---------------- K4: cws[i][bo] -> out[bo][i] transpose ----------------
__global__ __launch_bounds__(256) void k4_tr(const float* __restrict__ cws,
                                             float* __restrict__ out)
{
    __shared__ float T[128][68];
    const int bo0 = ((int)blockIdx.x & 127) * 64;
    const int ic  = (int)blockIdx.x >> 7;            // 0..7
    const int ni  = (ic == 7) ? 120 : 128;           // 1016 = 7*128 + 120
    const int t   = threadIdx.x;

    #pragma unroll
    for (int j = 0; j < 32; ++j) {
        int e = t + j * 256;
        int iloc = e >> 4, boq = (e & 15) * 4;
        if (iloc < ni)
            *(f32x4*)&T[iloc][boq] =
                *(const f32x4*)&cws[(size_t)(ic * 128 + iloc) * 8192 + bo0 + boq];
    }
    __syncthreads();

    const int boloc = t >> 2, ig = t & 3;
    #pragma unroll
    for (int jj = 0; jj < 8; ++jj) {
        int ii = ig * 32 + jj * 4;
        if (ii + 4 <= ni) {
            f32x4 v = {T[ii][boloc], T[ii + 1][boloc], T[ii + 2][boloc], T[ii + 3][boloc]};
            *(f32x4*)&out[(size_t)(bo0 + boloc) * LOUT + ic * 128 + ii] = v;
        }
    }
}

// ---------------- fallback (tiny ws): direct scattered-read GEMM ----------------
__global__ __launch_bounds__(512, 4) void lc1d_legacy(
    const float* __restrict__ x, const float* __restrict__ w,
    const float* __restrict__ bias, float* __restrict__ out)
{
    const int i    = ((int)(blockIdx.x & 7)) * 127 + ((int)blockIdx.x >> 3);
    const int tid  = threadIdx.x;
    const int lane = tid & 63;
    const int wid  = tid >> 6;
    const int wm   = wid >> 1;
    const int wn   = wid & 1;
    const int l16  = lane & 15;
    const int l4   = lane >> 4;

    __shared__ unsigned short Alds[128][40];
    __shared__ unsigned short Blds[64][40];

    f32x4 acc[2][2];
    #pragma unroll
    for (int a = 0; a < 2; ++a)
        #pragma unroll
        for (int b = 0; b < 2; ++b)
            acc[a][b] = (f32x4){0.f, 0.f, 0.f, 0.f};

    for (int tch = 0; tch < 18; ++tch) {
        const int q0 = tch * 32;
        #pragma unroll
        for (int j = 0; j < 4; ++j) {
            int e = tid + j * 512;
            int o = e >> 5, qq = e & 31;
            int q = q0 + qq;
            int c = q / 9, k = q - 9 * c;
            Blds[o][qq] = f2bf(w[((size_t)(o * CIN + c) * LOUT + i) * KW + k]);
        }
        #pragma unroll
        for (int j = 0; j < 8; ++j) {
            int e = tid + j * 512;
            int b = e >> 5, qq = e & 31;
            int q = q0 + qq;
            int c = q / 9, k = q - 9 * c;
            Alds[b][qq] = f2bf(x[(size_t)(b * CIN + c) * LIN + i + k]);
        }
        __syncthreads();
        bf16x8 af[2], bfr[2];
        #pragma unroll
        for (int mf = 0; mf < 2; ++mf)
            af[mf] = *reinterpret_cast<const bf16x8*>(&Alds[wm * 32 + mf * 16 + l16][l4 * 8]);
        #pragma unroll
        for (int nf = 0; nf < 2; ++nf)
            bfr[nf] = *reinterpret_cast<const bf16x8*>(&Blds[wn * 32 + nf * 16 + l16][l4 * 8]);
        #pragma unroll
        for (int mf = 0; mf < 2; ++mf)
            #pragma unroll
            for (int nf = 0; nf < 2; ++nf)
                acc[mf][nf] = __builtin_amdgcn_mfma_f32_16x16x32_bf16(af[mf], bfr[nf], acc[mf][nf], 0, 0, 0);
        __syncthreads();
    }
    #pragma unroll
    for (int nf = 0; nf < 2; ++nf) {
        int o = wn * 32 + nf * 16 + l16;
        float bv = 64.0f * bias[o * LOUT + i];
        #pragma unroll
        for (int mf = 0; mf < 2; ++mf)
            #pragma unroll
            for (int j = 0; j < 4; ++j) {
                int b = wm * 32 + mf * 16 + l4 * 4 + j;
                out[((size_t)b * 64 + o) * LOUT + i] = acc[mf][nf][j] + bv;
            }
    }
}

extern "C" void kernel_launch(void* const* d_in, const int* in_sizes, int n_in,
                              void* d_out, int out_size, void* d_ws, size_t ws_size,
                              hipStream_t stream) {
    const float* x    = (const float*)d_in[0];
    const float* w    = (const float*)d_in[1];
    const float* bias = (const float*)d_in[2];
    float* out        = (float*)d_out;

    const size_t W2B = (size_t)LOUT * 64 * 576 * 2;      // 74,907,648
    const size_t XTB = (size_t)1024 * 128 * 64 * 2;      // 16,777,216
    const size_t CWB = (size_t)LOUT * 8192 * 4;          // 33,292,288

    if (ws_size < W2B + XTB + CWB) {
        lc1d_legacy<<<dim3(LOUT), dim3(512), 0, stream>>>(x, w, bias, out);
        return;
    }
    unsigned short* w2 = (unsigned short*)d_ws;
    unsigned short* xt = (unsigned short*)((char*)d_ws + W2B);
    float*          cw = (float*)((char*)d_ws + W2B + XTB);

    k1_xt <<<dim3(512),  dim3(512), 0, stream>>>(x, xt);
    k2_w2 <<<dim3(2048), dim3(512), 0, stream>>>(w, w2);
    k3e   <<<dim3(LOUT), dim3(512), 0, stream>>>(xt, w2, bias, cw);
    k4_tr <<<dim3(1024), dim3(256), 0, stream>>>(cw, out);
}

// Round 6
// 89.797 us; speedup vs baseline: 2.2827x; 1.2246x over previous
//
#include <hip/hip_runtime.h>

// LocallyConnected1d: out[b,o,i] = sum_{c,k} x[b,c,i+k] * w[o,c,i,k] + 64*bias[o,i]
// B=128, C_IN=64, C_OUT=64, L=1024, K=9, L_OUT=1016
//
// R6: 2-kernel pipeline. k1: x -> xt[l][b*64+c] bf16 (measured ~8us).
// kf: fused GEMM. Block = 8 i x 16 o x 128 b, 8 c-chunks of 8.
//   - w read DIRECTLY (f32, once): per (o,c) a 288-B contiguous run, reg-staged,
//     cvt->bf16, swizzled ds_write. k padded 9->12 (pad pre-zeroed once).
//   - xt staged via global_load_lds, XOR-swizzled source+read (rule #21).
//   - counted waits: manual vmcnt(0) placed where ONLY the 4 A-loads are
//     outstanding; w(cc+1) issued after the barrier -> flies across compute (T14).
//   - epilogue: 2-pass LDS transpose -> 32-B aligned i-runs straight to out.
// Eliminates k2 (225 MB) and k4 (66 MB) from R5's pipeline.

#define LIN  1024
#define LOUT 1016

typedef __attribute__((ext_vector_type(4))) float f32x4;
typedef __attribute__((ext_vector_type(8))) short bf16x8;

typedef const __attribute__((address_space(1))) unsigned int* gptr_t;
typedef __attribute__((address_space(3))) unsigned int* lptr_t;

static __device__ __forceinline__ unsigned short f2bf(float f) {
    unsigned int u = __float_as_uint(f);
    u += 0x7fffu + ((u >> 16) & 1u);   // round-to-nearest-even
    return (unsigned short)(u >> 16);
}

// ---------------- K1: x[b][c][l] f32 -> xt[l][b*64+c] bf16 ----------------
__global__ __launch_bounds__(512) void k1_xt(const float* __restrict__ x,
                                             unsigned short* __restrict__ xt)
{
    __shared__ unsigned int T3[64][36];
    const int t  = threadIdx.x;
    const int b0 = ((int)blockIdx.x >> 4) * 4;
    const int l0 = ((int)blockIdx.x & 15) * 64;
    const int cp = t >> 4;
    const int lq = t & 15;

    for (int bb = 0; bb < 4; ++bb) {
        const int b = b0 + bb;
        const f32x4* x4 = (const f32x4*)x;
        f32x4 fa = x4[(size_t)(b * 64 + 2 * cp) * 256 + (l0 >> 2) + lq];
        f32x4 fb = x4[(size_t)(b * 64 + 2 * cp + 1) * 256 + (l0 >> 2) + lq];
        #pragma unroll
        for (int m = 0; m < 4; ++m) {
            unsigned int pk = (unsigned int)f2bf(fa[m]) | ((unsigned int)f2bf(fb[m]) << 16);
            T3[lq * 4 + m][cp] = pk;
        }
        __syncthreads();
        {
            const int lp = t >> 3;
            const int fq = t & 7;
            uint4 v = *(const uint4*)&T3[lp][fq * 4];
            *(uint4*)&xt[(size_t)(l0 + lp) * 8192 + b * 64 + fq * 8] = v;
        }
        __syncthreads();
    }
}

// ---------------- KF: fused GEMM ----------------
// LDS (57344 B static):
//   A @0     : [16 rows][128 b-slots][8 c] bf16 = 32768 B, slot holds
//              b_src = (slot&112) | ((slot ^ row)&15)   (bank swizzle)
//   B @32768 : [8 i][12 k][16 o-slots][8 c] bf16 = 24576 B, slot o' = o ^ k;
//              k=9..11 pre-zeroed (never rewritten)
//   epilogue overlay: Cb[64][16][8] f32 = 32768 B
__global__ __launch_bounds__(512, 4) void kf(const unsigned short* __restrict__ xt,
                                             const float* __restrict__ w,
                                             const float* __restrict__ bias,
                                             float* __restrict__ out)
{
    __shared__ __align__(16) char smem[57344];

    // bijective XCD-chunked swizzle over 508 blocks (q=63, r=4; m204 formula)
    const int orig = (int)blockIdx.x;
    const int xcd = orig & 7, sx = orig >> 3;
    const int vid = (xcd < 4) ? xcd * 64 + sx : 256 + (xcd - 4) * 63 + sx;
    const int it = vid >> 2, ob = vid & 3;
    const int i0 = it * 8, o0 = ob * 16;

    const int t    = threadIdx.x;
    const int wid  = t >> 6;
    const int lane = t & 63;
    const int l16  = lane & 15, l4 = lane >> 4;

    // ---- zero B's k=9..11 pad (once; cvt only writes k 0..8) ----
    {
        unsigned int* B32 = (unsigned int*)(smem + 32768);
        #pragma unroll
        for (int r = 0; r < 3; ++r) {
            int z = t + r * 512;                 // 0..1535
            int zi = z / 192, rem = z - zi * 192;
            B32[(zi * 12 + 9) * 64 + rem] = 0u;
        }
    }

    // w staging role: thread -> (iw, ow, cp): two 9-float runs (c = cc*8+cp*2+{0,1})
    const int iw = t >> 6, ow = (t >> 2) & 15, cpc = t & 3;

    float wr[18];
    {
        const float* p0 = w + (size_t)((o0 + ow) * 64 + cpc * 2) * (LOUT * 9)
                            + (size_t)(i0 + iw) * 9;
        __builtin_memcpy(&wr[0], p0, 36);
        __builtin_memcpy(&wr[9], p0 + (size_t)LOUT * 9, 36);
    }

    f32x4 acc[8];
    #pragma unroll
    for (int m = 0; m < 8; ++m) acc[m] = (f32x4){0.f, 0.f, 0.f, 0.f};

    for (int cc = 0; cc < 8; ++cc) {
        // ---- issue A(cc): 4 gload_lds per wave, source pre-swizzled ----
        __builtin_amdgcn_sched_barrier(0);
        #pragma unroll
        for (int ri = 0; ri < 2; ++ri) {
            const int row = wid * 2 + ri;
            #pragma unroll
            for (int half = 0; half < 2; ++half) {
                const int b_slot = half * 64 + lane;
                const int b_src  = (b_slot & 112) | ((b_slot ^ row) & 15);
                const unsigned short* src = xt + (size_t)(i0 + row) * 8192 + b_src * 64 + cc * 8;
                __builtin_amdgcn_global_load_lds((gptr_t)(const void*)src,
                    (lptr_t)(void*)(smem + (row * 128 + half * 64) * 16), 16, 0, 0);
            }
        }
        __builtin_amdgcn_sched_barrier(0);

        // ---- cvt w(cc) -> swizzled B writes (compiler auto-waits w regs @vmcnt(4)) ----
        {
            unsigned int* B32 = (unsigned int*)(smem + 32768);
            #pragma unroll
            for (int k = 0; k < 9; ++k) {
                unsigned int v = (unsigned int)f2bf(wr[k]) | ((unsigned int)f2bf(wr[9 + k]) << 16);
                B32[((iw * 12 + k) * 16 + (ow ^ k)) * 4 + cpc] = v;
            }
        }
        // only the 4 A gload_lds are outstanding here -> count-safe full wait
        asm volatile("s_waitcnt lgkmcnt(0)" ::: "memory");
        asm volatile("s_waitcnt vmcnt(0)" ::: "memory");
        __builtin_amdgcn_sched_barrier(0);
        __builtin_amdgcn_s_barrier();           // A+B ready for all waves
        __builtin_amdgcn_sched_barrier(0);

        // ---- T14: issue w(cc+1) now; flies across the whole compute phase ----
        if (cc < 7) {
            const float* p0 = w + (size_t)((o0 + ow) * 64 + (cc + 1) * 8 + cpc * 2) * (LOUT * 9)
                                + (size_t)(i0 + iw) * 9;
            __builtin_memcpy(&wr[0], p0, 36);
            __builtin_memcpy(&wr[9], p0 + (size_t)LOUT * 9, 36);
        }

        // ---- compute: wave = i (wid), 3 K-chunks of 32 (8c x 4k), 8 m-frags ----
        {
            const char* Ab = smem;
            const char* Bb = smem + 32768;
            #pragma unroll
            for (int kp = 0; kp < 3; ++kp) {
                const int kb = kp * 4 + l4;                      // k index 0..11
                bf16x8 bf = *(const bf16x8*)(Bb + (((wid * 12 + kb) * 16 + (l16 ^ kb)) << 4));
                int rowc = wid + kb; rowc = rowc > 15 ? 15 : rowc;  // clamp: k>=9 rows are x0
                const char* arow = Ab + ((rowc * 128 + (l16 ^ rowc)) << 4);
                #pragma unroll
                for (int m = 0; m < 8; ++m) {
                    bf16x8 af = *(const bf16x8*)(arow + (m << 8));
                    acc[m] = __builtin_amdgcn_mfma_f32_16x16x32_bf16(af, bf, acc[m], 0, 0, 0);
                }
            }
        }
        __builtin_amdgcn_sched_barrier(0);
        __builtin_amdgcn_s_barrier();           // compute done; bufs free
        __builtin_amdgcn_sched_barrier(0);
    }

    // ---- epilogue: 2 passes of acc -> Cb[64][16][8] -> 32-B i-runs to out ----
    // C/D layout (m89): col = lane&15 (=o), row = (lane>>4)*4 + reg (=b within 16)
    float* Cb = (float*)smem;
    #pragma unroll
    for (int p = 0; p < 2; ++p) {
        if (p) __syncthreads();
        #pragma unroll
        for (int mm = 0; mm < 4; ++mm) {
            #pragma unroll
            for (int j = 0; j < 4; ++j) {
                const int b_loc = mm * 16 + l4 * 4 + j;
                Cb[(b_loc * 16 + l16) * 8 + wid] = acc[p * 4 + mm][j];
            }
        }
        __syncthreads();
        #pragma unroll
        for (int s2 = 0; s2 < 2; ++s2) {
            const int e = t * 2 + s2;
            const int b_loc = e >> 4, o = e & 15;
            const float* cb = &Cb[(b_loc * 16 + o) * 8];
            f32x4 v0 = *(const f32x4*)cb;
            f32x4 v1 = *(const f32x4*)(cb + 4);
            const float* bp = &bias[(size_t)(o0 + o) * LOUT + i0];
            f32x4 bv0 = *(const f32x4*)bp;
            f32x4 bv1 = *(const f32x4*)(bp + 4);
            float* op = &out[((size_t)(p * 64 + b_loc) * 64 + o0 + o) * LOUT + i0];
            *(f32x4*)op       = v0 + 64.0f * bv0;
            *(f32x4*)(op + 4) = v1 + 64.0f * bv1;
        }
    }
}

// ---------------- fallback (tiny ws): direct scattered-read GEMM ----------------
__global__ __launch_bounds__(512, 4) void lc1d_legacy(
    const float* __restrict__ x, const float* __restrict__ w,
    const float* __restrict__ bias, float* __restrict__ out)
{
    const int i    = ((int)(blockIdx.x & 7)) * 127 + ((int)blockIdx.x >> 3);
    const int tid  = threadIdx.x;
    const int lane = tid & 63;
    const int wid  = tid >> 6;
    const int wm   = wid >> 1;
    const int wn   = wid & 1;
    const int l16  = lane & 15;
    const int l4   = lane >> 4;

    __shared__ unsigned short Alds[128][40];
    __shared__ unsigned short Blds[64][40];

    f32x4 acc[2][2];
    #pragma unroll
    for (int a = 0; a < 2; ++a)
        #pragma unroll
        for (int b = 0; b < 2; ++b)
            acc[a][b] = (f32x4){0.f, 0.f, 0.f, 0.f};

    for (int tch = 0; tch < 18; ++tch) {
        const int q0 = tch * 32;
        #pragma unroll
        for (int j = 0; j < 4; ++j) {
            int e = tid + j * 512;
            int o = e >> 5, qq = e & 31;
            int q = q0 + qq;
            int c = q / 9, k = q - 9 * c;
            Blds[o][qq] = f2bf(w[((size_t)(o * 64 + c) * LOUT + i) * 9 + k]);
        }
        #pragma unroll
        for (int j = 0; j < 8; ++j) {
            int e = tid + j * 512;
            int b = e >> 5, qq = e & 31;
            int q = q0 + qq;
            int c = q / 9, k = q - 9 * c;
            Alds[b][qq] = f2bf(x[(size_t)(b * 64 + c) * LIN + i + k]);
        }
        __syncthreads();
        bf16x8 af[2], bfr[2];
        #pragma unroll
        for (int mf = 0; mf < 2; ++mf)
            af[mf] = *reinterpret_cast<const bf16x8*>(&Alds[wm * 32 + mf * 16 + l16][l4 * 8]);
        #pragma unroll
        for (int nf = 0; nf < 2; ++nf)
            bfr[nf] = *reinterpret_cast<const bf16x8*>(&Blds[wn * 32 + nf * 16 + l16][l4 * 8]);
        #pragma unroll
        for (int mf = 0; mf < 2; ++mf)
            #pragma unroll
            for (int nf = 0; nf < 2; ++nf)
                acc[mf][nf] = __builtin_amdgcn_mfma_f32_16x16x32_bf16(af[mf], bfr[nf], acc[mf][nf], 0, 0, 0);
        __syncthreads();
    }
    #pragma unroll
    for (int nf = 0; nf < 2; ++nf) {
        int o = wn * 32 + nf * 16 + l16;
        float bv = 64.0f * bias[o * LOUT + i];
        #pragma unroll
        for (int mf = 0; mf < 2; ++mf)
            #pragma unroll
            for (int j = 0; j < 4; ++j) {
                int b = wm * 32 + mf * 16 + l4 * 4 + j;
                out[((size_t)b * 64 + o) * LOUT + i] = acc[mf][nf][j] + bv;
            }
    }
}

extern "C" void kernel_launch(void* const* d_in, const int* in_sizes, int n_in,
                              void* d_out, int out_size, void* d_ws, size_t ws_size,
                              hipStream_t stream) {
    const float* x    = (const float*)d_in[0];
    const float* w    = (const float*)d_in[1];
    const float* bias = (const float*)d_in[2];
    float* out        = (float*)d_out;

    const size_t XTB = (size_t)1024 * 128 * 64 * 2;   // 16,777,216

    if (ws_size < XTB) {
        lc1d_legacy<<<dim3(LOUT), dim3(512), 0, stream>>>(x, w, bias, out);
        return;
    }
    unsigned short* xt = (unsigned short*)d_ws;

    k1_xt<<<dim3(512), dim3(512), 0, stream>>>(x, xt);
    kf   <<<dim3(508), dim3(512), 0, stream>>>(xt, w, bias, out);
}

// Round 7
// 61.491 us; speedup vs baseline: 3.3336x; 1.4603x over previous
//
#include <hip/hip_runtime.h>

// LocallyConnected1d: out[b,o,i] = sum_{c,k} x[b,c,i+k] * w[o,c,i,k] + 64*bias[o,i]
// B=128, C_IN=64, C_OUT=64, L=1024, K=9, L_OUT=1016
//
// R7: sector-clean fused pipeline (pump model: per-CU load pump ~10B/cy counts ALL
// moved bytes; R6 lost to 4x sector amplification on strided A staging).
//   k1b: x[b][c][l] -> xt2[l][cc][b][c8] bf16. 64-B-run reads (4 lanes/run role),
//        LDS transpose (skewed), 2-KB contiguous piece writes.
//   kf2: block = 8i x 16o x 128b. A: global_load_lds from xt2 (linear, coalesced).
//        w: direct f32 reads, 4-lanes-per-run f32x4 role (full sectors), reg->cvt->
//        swizzled ds_write_b16 into double-buffered B. Counted vmcnt(5). Epilogue:
//        LDS transpose -> 32-B i-run stores (R6-proven, WRITE~40MB).

#define LIN  1024
#define LOUT 1016

typedef __attribute__((ext_vector_type(4))) float f32x4;
typedef __attribute__((ext_vector_type(8))) short bf16x8;

typedef const __attribute__((address_space(1))) unsigned int* gptr_t;
typedef __attribute__((address_space(3))) unsigned int* lptr_t;

static __device__ __forceinline__ unsigned short f2bf(float f) {
    unsigned int u = __float_as_uint(f);
    u += 0x7fffu + ((u >> 16) & 1u);   // round-to-nearest-even
    return (unsigned short)(u >> 16);
}

// ---------------- K1b: x[b][c][l] f32 -> xt2[(l*8+cc)*1024 + b*8 + c] bf16 ----------------
// grid 512 = 64 l-tiles(16) x 8 c-chunks. Reads: 64-B runs, 4 lanes/run (full sectors).
__global__ __launch_bounds__(512) void k1b(const float* __restrict__ x,
                                           unsigned short* __restrict__ xt2)
{
    __shared__ unsigned short T[16 * 1032 + 8];   // [l][b*8+c], l-stride 1032 (bank skew)
    const int t    = threadIdx.x;
    const int lane = t & 63;
    const int wid  = t >> 6;
    const int lt   = (int)blockIdx.x >> 3;
    const int cc   = (int)blockIdx.x & 7;
    const int l0   = lt * 16;
    const int rl   = lane >> 2;      // run-local 0..15
    const int pos  = lane & 3;

    #pragma unroll
    for (int s = 0; s < 8; ++s) {
        int r = s * 128 + wid * 16 + rl;          // 0..1023 : (b, c_local)
        int b = r >> 3, cl = r & 7;
        f32x4 v = *(const f32x4*)&x[(size_t)(b * 64 + cc * 8 + cl) * 1024 + l0 + pos * 4];
        #pragma unroll
        for (int j = 0; j < 4; ++j)
            T[(pos * 4 + j) * 1032 + b * 8 + cl] = f2bf(v[j]);
    }
    __syncthreads();
    #pragma unroll
    for (int j2 = 0; j2 < 4; ++j2) {
        int e = j2 * 512 + t;                     // uint4 index 0..2047
        int l = e >> 7, m = e & 127;
        uint4 v = *(const uint4*)&T[l * 1032 + m * 8];
        *(uint4*)&xt2[((size_t)(l0 + l) * 8 + cc) * 1024 + m * 8] = v;
    }
}

// ---------------- KF2: fused GEMM ----------------
// LDS: A @0 [16 row][128 b][8 c] bf16 = 32768 (linear, gload_lds dest)
//      B @32768: 2 bufs x [e=i*9+k][16 o-slot][8 c] (slot = o ^ (e&15)) = 2x18432
//      zslab @69632: 768 B zeros (kb 9..11 fragment reads)
//      epilogue Cb overlays A (32 KB)
__global__ __launch_bounds__(512, 4) void kf2(const unsigned short* __restrict__ xt2,
                                              const float* __restrict__ w,
                                              const float* __restrict__ bias,
                                              float* __restrict__ out)
{
    __shared__ __align__(16) char smem[70400];

    // bijective XCD-chunked swizzle over 508 blocks (q=63, r=4)
    const int orig = (int)blockIdx.x;
    const int xcd = orig & 7, sx = orig >> 3;
    const int vid = (xcd < 4) ? xcd * 64 + sx : 256 + (xcd - 4) * 63 + sx;
    const int it = vid >> 2, ob = vid & 3;
    const int i0 = it * 8, o0 = ob * 16;

    const int t    = threadIdx.x;
    const int wid  = t >> 6;          // wave = local i
    const int lane = t & 63;
    const int l16  = lane & 15, l4 = lane >> 4;

    // w staging role: run (ow, cl), 4 lanes per run
    const int ow  = wid * 2 + (lane >> 5);     // 0..15
    const int cl  = (lane >> 2) & 7;           // 0..7
    const int pos = lane & 3;

    // zero slab init
    if (t < 192) *(unsigned int*)(smem + 69632 + t * 4) = 0u;

    f32x4 acc[8];
    #pragma unroll
    for (int m = 0; m < 8; ++m) acc[m] = (f32x4){0.f, 0.f, 0.f, 0.f};

    f32x4 wreg[2][5];

#define ISSUE_W(slot, ccw) { \
        const float* rb = w + (size_t)((o0 + ow) * 64 + (ccw) * 8 + cl) * 9144 + (size_t)i0 * 9; \
        wreg[slot][0] = *(const f32x4*)(rb + pos * 4); \
        wreg[slot][1] = *(const f32x4*)(rb + 16 + pos * 4); \
        wreg[slot][2] = *(const f32x4*)(rb + 32 + pos * 4); \
        wreg[slot][3] = *(const f32x4*)(rb + 48 + pos * 4); \
        if (pos < 2) wreg[slot][4] = *(const f32x4*)(rb + 64 + pos * 4); \
    }

#define CVT_W(slot, buf) { \
        unsigned short* Bd = (unsigned short*)(smem + 32768 + (buf) * 18432); \
        _Pragma("unroll") \
        for (int sv = 0; sv < 4; ++sv) { \
            _Pragma("unroll") \
            for (int j = 0; j < 4; ++j) { \
                int e = sv * 16 + pos * 4 + j; \
                Bd[e * 128 + ((ow ^ (e & 15)) << 3) + cl] = f2bf(wreg[slot][sv][j]); \
            } \
        } \
        if (pos < 2) { \
            _Pragma("unroll") \
            for (int j = 0; j < 4; ++j) { \
                int e = 64 + pos * 4 + j; \
                Bd[e * 128 + ((ow ^ (e & 15)) << 3) + cl] = f2bf(wreg[slot][4][j]); \
            } \
        } \
    }

#define ISSUE_A(cca) { \
        _Pragma("unroll") \
        for (int jj = 0; jj < 4; ++jj) { \
            int jA = wid * 4 + jj; \
            const unsigned short* src = xt2 + ((size_t)(i0 + (jA >> 1)) * 8 + (cca)) * 1024 \
                                            + (jA & 1) * 512 + lane * 8; \
            __builtin_amdgcn_global_load_lds((gptr_t)(const void*)src, \
                (lptr_t)(void*)(smem + jA * 1024), 16, 0, 0); \
        } \
    }

#define COMPUTE(buf) { \
        _Pragma("unroll") \
        for (int kp = 0; kp < 3; ++kp) { \
            const int kb = kp * 4 + l4; \
            const int e  = wid * 9 + kb; \
            const char* baddr = (kb < 9) \
                ? (smem + 32768 + (buf) * 18432 + (e * 128 + ((l16 ^ (e & 15)) << 3)) * 2) \
                : (smem + 69632 + ((kb - 9) * 16 + l16) * 16); \
            bf16x8 bfr = *(const bf16x8*)baddr; \
            int rowc = wid + kb; rowc = rowc > 15 ? 15 : rowc; \
            const char* arow = smem + (rowc * 128 + l16) * 16; \
            _Pragma("unroll") \
            for (int m = 0; m < 8; ++m) { \
                bf16x8 af = *(const bf16x8*)(arow + (m << 8)); \
                acc[m] = __builtin_amdgcn_mfma_f32_16x16x32_bf16(af, bfr, acc[m], 0, 0, 0); \
            } \
        } \
    }

    // prologue
    ISSUE_A(0);
    ISSUE_W(0, 0);
    ISSUE_W(1, 1);
    CVT_W(0, 0);                                  // compiler drains w(0) (A drains too)
    asm volatile("s_waitcnt vmcnt(5)" ::: "memory");
    asm volatile("s_waitcnt lgkmcnt(0)" ::: "memory");
    __builtin_amdgcn_sched_barrier(0);
    __builtin_amdgcn_s_barrier();

    #pragma unroll
    for (int cc = 0; cc < 8; ++cc) {
        COMPUTE(cc & 1);
        __builtin_amdgcn_sched_barrier(0);
        __builtin_amdgcn_s_barrier();             // all reads of A & B[cc&1] done
        if (cc < 7) {
            ISSUE_A(cc + 1);                      // oldest outstanding -> drained by vmcnt(5)
            if (cc < 6) ISSUE_W(cc & 1, cc + 2);  // newest; stays in flight
            CVT_W((cc + 1) & 1, (cc + 1) & 1);    // compiler auto-drains w(cc+1)
            if (cc < 6) { asm volatile("s_waitcnt vmcnt(5)" ::: "memory"); }
            else        { asm volatile("s_waitcnt vmcnt(0)" ::: "memory"); }
            asm volatile("s_waitcnt lgkmcnt(0)" ::: "memory");
            __builtin_amdgcn_sched_barrier(0);
            __builtin_amdgcn_s_barrier();
        }
    }

    // ---- epilogue: acc -> Cb[64 b][16 o][8 i] (overlay A), 32-B i-run stores ----
    // C/D layout (m89): col = lane&15 (=o), row = (lane>>4)*4 + reg (=b within 16)
    float* Cb = (float*)smem;
    #pragma unroll
    for (int p = 0; p < 2; ++p) {
        if (p) __syncthreads();
        #pragma unroll
        for (int mm = 0; mm < 4; ++mm) {
            #pragma unroll
            for (int j = 0; j < 4; ++j) {
                const int b_loc = mm * 16 + l4 * 4 + j;
                Cb[(b_loc * 16 + l16) * 8 + wid] = acc[p * 4 + mm][j];
            }
        }
        __syncthreads();
        #pragma unroll
        for (int s2 = 0; s2 < 2; ++s2) {
            const int e = t * 2 + s2;
            const int b_loc = e >> 4, o = e & 15;
            const float* cb = &Cb[(b_loc * 16 + o) * 8];
            f32x4 v0 = *(const f32x4*)cb;
            f32x4 v1 = *(const f32x4*)(cb + 4);
            const float* bp = &bias[(size_t)(o0 + o) * LOUT + i0];
            f32x4 bv0 = *(const f32x4*)bp;
            f32x4 bv1 = *(const f32x4*)(bp + 4);
            float* op = &out[((size_t)(p * 64 + b_loc) * 64 + o0 + o) * LOUT + i0];
            *(f32x4*)op       = v0 + 64.0f * bv0;
            *(f32x4*)(op + 4) = v1 + 64.0f * bv1;
        }
    }
#undef ISSUE_W
#undef CVT_W
#undef ISSUE_A
#undef COMPUTE
}

// ---------------- fallback (tiny ws): direct scattered-read GEMM ----------------
__global__ __launch_bounds__(512, 4) void lc1d_legacy(
    const float* __restrict__ x, const float* __restrict__ w,
    const float* __restrict__ bias, float* __restrict__ out)
{
    const int i    = ((int)(blockIdx.x & 7)) * 127 + ((int)blockIdx.x >> 3);
    const int tid  = threadIdx.x;
    const int lane = tid & 63;
    const int wid  = tid >> 6;
    const int wm   = wid >> 1;
    const int wn   = wid & 1;
    const int l16  = lane & 15;
    const int l4   = lane >> 4;

    __shared__ unsigned short Alds[128][40];
    __shared__ unsigned short Blds[64][40];

    f32x4 acc[2][2];
    #pragma unroll
    for (int a = 0; a < 2; ++a)
        #pragma unroll
        for (int b = 0; b < 2; ++b)
            acc[a][b] = (f32x4){0.f, 0.f, 0.f, 0.f};

    for (int tch = 0; tch < 18; ++tch) {
        const int q0 = tch * 32;
        #pragma unroll
        for (int j = 0; j < 4; ++j) {
            int e = tid + j * 512;
            int o = e >> 5, qq = e & 31;
            int q = q0 + qq;
            int c = q / 9, k = q - 9 * c;
            Blds[o][qq] = f2bf(w[((size_t)(o * 64 + c) * LOUT + i) * 9 + k]);
        }
        #pragma unroll
        for (int j = 0; j < 8; ++j) {
            int e = tid + j * 512;
            int b = e >> 5, qq = e & 31;
            int q = q0 + qq;
            int c = q / 9, k = q - 9 * c;
            Alds[b][qq] = f2bf(x[(size_t)(b * 64 + c) * LIN + i + k]);
        }
        __syncthreads();
        bf16x8 af[2], bfr[2];
        #pragma unroll
        for (int mf = 0; mf < 2; ++mf)
            af[mf] = *reinterpret_cast<const bf16x8*>(&Alds[wm * 32 + mf * 16 + l16][l4 * 8]);
        #pragma unroll
        for (int nf = 0; nf < 2; ++nf)
            bfr[nf] = *reinterpret_cast<const bf16x8*>(&Blds[wn * 32 + nf * 16 + l16][l4 * 8]);
        #pragma unroll
        for (int mf = 0; mf < 2; ++mf)
            #pragma unroll
            for (int nf = 0; nf < 2; ++nf)
                acc[mf][nf] = __builtin_amdgcn_mfma_f32_16x16x32_bf16(af[mf], bfr[nf], acc[mf][nf], 0, 0, 0);
        __syncthreads();
    }
    #pragma unroll
    for (int nf = 0; nf < 2; ++nf) {
        int o = wn * 32 + nf * 16 + l16;
        float bv = 64.0f * bias[o * LOUT + i];
        #pragma unroll
        for (int mf = 0; mf < 2; ++mf)
            #pragma unroll
            for (int j = 0; j < 4; ++j) {
                int b = wm * 32 + mf * 16 + l4 * 4 + j;
                out[((size_t)b * 64 + o) * LOUT + i] = acc[mf][nf][j] + bv;
            }
    }
}

extern "C" void kernel_launch(void* const* d_in, const int* in_sizes, int n_in,
                              void* d_out, int out_size, void* d_ws, size_t ws_size,
                              hipStream_t stream) {
    const float* x    = (const float*)d_in[0];
    const float* w    = (const float*)d_in[1];
    const float* bias = (const float*)d_in[2];
    float* out        = (float*)d_out;

    const size_t XTB = (size_t)1024 * 8192 * 2;   // 16,777,216

    if (ws_size < XTB) {
        lc1d_legacy<<<dim3(LOUT), dim3(512), 0, stream>>>(x, w, bias, out);
        return;
    }
    unsigned short* xt2 = (unsigned short*)d_ws;

    k1b<<<dim3(512), dim3(512), 0, stream>>>(x, xt2);
    kf2<<<dim3(508), dim3(512), 0, stream>>>(xt2, w, bias, out);
}